// Round 12
// baseline (109.476 us; speedup 1.0000x reference)
//
#include <hip/hip_runtime.h>

// qg_flux, round 12: 16x16 grid (sliver blocks eliminated — boundary rows/cols
// of every field are identically zero via _pad1). zfill_k writes the i=512 /
// j=512 output lines; K2/K3 staging treats pA/pB/q1 outside the interior as 0
// (bit-identical). Otherwise identical to round 11.

#define N0 513
#define N1 257
#define NB 16
#define NT 512

#define C0F ((float)(1.0 / 4.006103515625))
#define D0F 4.006103515625f
#define C1F ((float)(1.0 / 4.0244140625))
#define H0SQ 3.814697265625e-06f            // h0^2 = 2^-18, exact
#define INV_DX2 262144.0f                   // 2^18
#define CENTER  1048576.0f                  // 4*2^18
#define INV12S  ((float)(262144.0 / 12.0 * 262144.0))  // INV12 * 2^18

// boundary lines i=512 / j=512 of both outputs are all-zero (_pad1)
__global__ __launch_bounds__(256) void zfill_k(float* __restrict__ psi_out,
                                               float* __restrict__ qf_out) {
  size_t b = (size_t)blockIdx.x * (N0 * N0);
  for (int t = threadIdx.x; t < N0; t += 256) {
    psi_out[b + (size_t)(N0 - 1) * N0 + t] = 0.f;
    psi_out[b + (size_t)t * N0 + (N0 - 1)] = 0.f;
    qf_out[b + (size_t)(N0 - 1) * N0 + t] = 0.f;
    qf_out[b + (size_t)t * N0 + (N0 - 1)] = 0.f;
  }
}

// ---- vertical-strip helpers (interior blocks only; no bounds checks) -------

template<int W, int H, int SL, int GS, bool SC>
__device__ __forceinline__ void stage_v(const float* __restrict__ g,
                                        int oi, int oj,
                                        float* __restrict__ s, int lid) {
  constexpr int RB = (H + 3) / 4;
  if (lid < W * RB) {
    int c = lid % W, rb = lid / W, r0 = rb * 4;
    const float* gp = g + (size_t)(oi + r0) * GS + (oj + c);
    #pragma unroll
    for (int k = 0; k < 4; k++) {
      if constexpr (H % 4 != 0) { if (r0 + k >= H) break; }
      float v = gp[k * GS];
      s[(r0 + k) * SL + c] = SC ? v * H0SQ : v;
    }
  }
}

template<int W, int H, int SI, int SQ, int SO, bool LAP>
__device__ __forceinline__ void sweep_v(const float* __restrict__ in,
                                        const float* __restrict__ qq,
                                        float* __restrict__ out, int lid) {
  constexpr int RB = (H + 3) / 4;
  if (lid < W * RB) {
    int c = lid % W, rb = lid / W, r0 = rb * 4;
    const float* colp = in + r0 * SI + (c + 1);
    float vn = colp[0];
    float vc = colp[SI];
    #pragma unroll
    for (int k = 0; k < 4; k++) {
      if constexpr (H % 4 != 0) { if (r0 + k >= H) break; }
      int r = r0 + k;
      float vs = colp[(k + 2) * SI];
      float wv = in[(r + 1) * SI + c];
      float ev = in[(r + 1) * SI + c + 2];
      float o;
      if constexpr (LAP)
        o = (vn + vs + wv + ev) * INV_DX2 - vc * CENTER;
      else
        o = C0F * (vn + vs + wv + ev - qq[r * SQ + c]);
      out[r * SO + c] = o;
      vn = vc; vc = vs;
    }
  }
}

template<int SI, int SQ, int SO>
__device__ __forceinline__ void sweep_v_store(const float* __restrict__ in,
                                              const float* __restrict__ qq,
                                              float* __restrict__ out,
                                              float* __restrict__ gout,
                                              int ti, int tj, int lid) {
  constexpr int W = 34, H = 34, RB = 9;
  if (lid < W * RB) {
    int c = lid % W, rb = lid / W, r0 = rb * 4;
    const float* colp = in + r0 * SI + (c + 1);
    float vn = colp[0];
    float vc = colp[SI];
    bool cin = (c >= 1 && c <= 32);
    #pragma unroll
    for (int k = 0; k < 4; k++) {
      if (r0 + k >= H) break;
      int r = r0 + k;
      float vs = colp[(k + 2) * SI];
      float wv = in[(r + 1) * SI + c];
      float ev = in[(r + 1) * SI + c + 2];
      float o = C0F * (vn + vs + wv + ev - qq[r * SQ + c]);
      out[r * SO + c] = o;
      if (cin && r >= 1 && r <= 32)
        gout[(size_t)(ti - 1 + r) * N0 + (tj - 1 + c)] = o;
      vn = vc; vc = vs;
    }
  }
}

// prolong with row-chain (interior): gi0 = ti-5+r0 is ODD (ti = 32*by).
__device__ __forceinline__ void prolong_v(const float* __restrict__ P,
                                          const float* __restrict__ sp1,
                                          float* __restrict__ bufA,
                                          int ti, int tj, int c0i, int c0j,
                                          int lid) {
  constexpr int W = 42, RB = 11;
  if (lid < W * RB) {
    int c = lid % W, rb = lid / W, r0 = rb * 4;
    int gj = tj - 5 + c;
    int c1 = (gj >> 1) - c0j;
    float wx = (gj & 1) ? 0.5f : 0.f;
    const float* gp = P + (size_t)(ti - 5 + r0) * N0 + gj;
    int m = (ti - 5 + r0) >> 1;
    const float* s0 = sp1 + (m - c0i) * 24 + c1;
    float a0 = s0[0],  b0 = s0[1];
    float a1 = s0[24], b1 = s0[25];
    float t0 = a0 + wx * (b0 - a0);
    float t1 = a1 + wx * (b1 - a1);
    bufA[r0 * 43 + c]       = gp[0]  + (t0 + 0.5f * (t1 - t0));  // gi odd
    bufA[(r0 + 1) * 43 + c] = gp[N0] + (t1 + 0.f);               // gi even
    if (r0 + 2 < 42) {
      float a2 = s0[48], b2 = s0[49];
      float t2 = a2 + wx * (b2 - a2);
      bufA[(r0 + 2) * 43 + c] = gp[2 * N0] + (t1 + 0.5f * (t2 - t1));
      bufA[(r0 + 3) * 43 + c] = gp[3 * N0] + (t2 + 0.f);
    }
  }
}

// ---------------------------------------------------------------- drelaxR ---
// K1 only (input PSIG has real boundary values -> full-range staging guards).
template<bool INT>
__device__ __forceinline__ void drelaxR_body(
    const float* __restrict__ P, const float* __restrict__ Q,
    float* __restrict__ outp, float* __restrict__ q1p,
    int ti, int tj, int ic0, int jc0, size_t base, size_t cbase, int lid,
    float* __restrict__ sIn, float* __restrict__ sQ,
    float* __restrict__ sT, float* __restrict__ sP) {
  const int n = N0;
  if constexpr (INT) {
    stage_v<38, 38, 39, N0, false>(P, ti - 3, tj - 3, sIn, lid);
    stage_v<36, 36, 37, N0, true>(Q, ti - 2, tj - 2, sQ, lid);
    __syncthreads();
    sweep_v<36, 36, 39, 37, 37, false>(sIn, sQ, sT, lid);
    __syncthreads();
    sweep_v_store<37, 37, 35>(sT, sQ + 38, sP, outp + base, ti, tj, lid);
    __syncthreads();
  } else {
    for (int t = lid; t < 38 * 38; t += NT) {
      int r = t / 38, c = t - r * 38;
      int gi = ti - 3 + r, gj = tj - 3 + c;
      sIn[r * 39 + c] = (gi >= 0 && gi < n && gj >= 0 && gj < n) ? P[(size_t)gi * n + gj] : 0.f;
    }
    for (int t = lid; t < 36 * 36; t += NT) {
      int r = t / 36, c = t - r * 36;
      int gi = ti - 2 + r, gj = tj - 2 + c;
      sQ[r * 37 + c] = (gi >= 0 && gi < n && gj >= 0 && gj < n) ? Q[(size_t)gi * n + gj] * H0SQ : 0.f;
    }
    __syncthreads();
    for (int t = lid; t < 36 * 36; t += NT) {
      int r = t / 36, c = t - r * 36;
      float v = 0.f;
      if ((ti - 2 + r) >= 1 && (ti - 2 + r) < n - 1 && (tj - 2 + c) >= 1 && (tj - 2 + c) < n - 1)
        v = C0F * (sIn[r * 39 + c + 1] + sIn[(r + 2) * 39 + c + 1] +
                   sIn[(r + 1) * 39 + c] + sIn[(r + 1) * 39 + c + 2] - sQ[r * 37 + c]);
      sT[r * 37 + c] = v;
    }
    __syncthreads();
    for (int t = lid; t < 34 * 34; t += NT) {
      int r = t / 34, c = t - r * 34;
      float v = 0.f;
      if ((ti - 1 + r) >= 1 && (ti - 1 + r) < n - 1 && (tj - 1 + c) >= 1 && (tj - 1 + c) < n - 1)
        v = C0F * (sT[r * 37 + c + 1] + sT[(r + 2) * 37 + c + 1] +
                   sT[(r + 1) * 37 + c] + sT[(r + 1) * 37 + c + 2] - sQ[(r + 1) * 37 + c + 1]);
      sP[r * 35 + c] = v;
      if (r >= 1 && r <= 32 && c >= 1 && c <= 32 && (ti - 1 + r) < n && (tj - 1 + c) < n)
        outp[base + (size_t)(ti - 1 + r) * n + (tj - 1 + c)] = v;
    }
    __syncthreads();
  }
  if (lid < 256) {
    int cy = lid >> 4, cx = lid & 15;
    int ic = ic0 + cy, jc = jc0 + cx;
    if (INT || (ic < N1 && jc < N1)) {
      float v = 0.f;
      if (INT || (ic >= 1 && ic < N1 - 1 && jc >= 1 && jc < N1 - 1)) {
        int r = 2 * cy + 1, c = 2 * cx + 1;
        v = 4.f * (D0F * sP[r * 35 + c] - sP[(r - 1) * 35 + c] - sP[(r + 1) * 35 + c]
                   - sP[r * 35 + c - 1] - sP[r * 35 + c + 1] + sQ[(r + 1) * 37 + c + 1]);
      }
      q1p[cbase + (size_t)ic * N1 + jc] = v;
    }
  }
}

__global__ __launch_bounds__(NT) void drelaxR_k(
    const float* __restrict__ psi, const float* __restrict__ Qg,
    float* __restrict__ out, float* __restrict__ q1) {
  __shared__ float smem[38 * 39 + 36 * 37 + 36 * 37];
  float* sIn = smem;
  float* sQ  = smem + 38 * 39;
  float* sT  = sQ + 36 * 37;
  float* sP  = smem;               // alias sIn (dead after s1)
  int bx = blockIdx.x, by = blockIdx.y;
  int ti = by * 32, tj = bx * 32;
  size_t base = (size_t)blockIdx.z * (N0 * N0);
  size_t cbase = (size_t)blockIdx.z * (N1 * N1);
  int lid = threadIdx.y * 32 + threadIdx.x;
  bool inter = (bx >= 1 && bx <= 14 && by >= 1 && by <= 14);
  if (inter)
    drelaxR_body<true>(psi + base, Qg + base, out, q1, ti, tj, 16 * by, 16 * bx,
                       base, cbase, lid, sIn, sQ, sT, sP);
  else
    drelaxR_body<false>(psi + base, Qg + base, out, q1, ti, tj, 16 * by, 16 * bx,
                        base, cbase, lid, sIn, sQ, sT, sP);
}

// ------------------------------------------------------- shared coarse prep --
// Used by K2/K3 only: P (= pA/pB) and q1 have zero boundaries by construction,
// so edge guards read them as 0 outside the interior (index 512/256 unwritten).
template<bool INT>
__device__ __forceinline__ void coarse_and_v(
    const float* __restrict__ P, const float* __restrict__ Q,
    const float* __restrict__ q1,
    int ti, int tj, int c0i, int c0j, int lid,
    float* __restrict__ bufA, float* __restrict__ bufB,
    float* __restrict__ sq1, float* __restrict__ sp1) {
  const int n = N0;
  if constexpr (INT) {
    stage_v<25, 25, 26, N1, false>(q1, c0i - 1, c0j - 1, sq1, lid);
    stage_v<40, 40, 41, N0, true>(Q, ti - 4, tj - 4, bufB, lid);
    __syncthreads();
    {
      constexpr int W = 23, RB = 6;
      if (lid < W * RB) {
        int c = lid % W, rb = lid / W, r0 = rb * 4;
        const float* colp = sq1 + r0 * 26 + (c + 1);
        float vn = colp[0];
        float vc = colp[26];
        #pragma unroll
        for (int k = 0; k < 4; k++) {
          if (r0 + k >= 23) break;
          int r = r0 + k;
          float vs = colp[(k + 2) * 26];
          float wv = sq1[(r + 1) * 26 + c];
          float ev = sq1[(r + 1) * 26 + c + 2];
          sp1[r * 24 + c] = C1F * (-C1F * (vn + vs + wv + ev) - vc);
          vn = vc; vc = vs;
        }
      }
    }
    __syncthreads();
    prolong_v(P, sp1, bufA, ti, tj, c0i, c0j, lid);
    __syncthreads();
  } else {
    for (int t = lid; t < 25 * 25; t += NT) {
      int r = t / 25, c = t - r * 25;
      int ci = c0i - 1 + r, cj = c0j - 1 + c;
      // q1 boundary is 0 by construction; indices 0 and 256 read as 0
      sq1[r * 26 + c] = (ci >= 1 && ci < N1 - 1 && cj >= 1 && cj < N1 - 1)
                        ? q1[(size_t)ci * N1 + cj] : 0.f;
    }
    for (int t = lid; t < 40 * 40; t += NT) {
      int r = t / 40, c = t - r * 40;
      int gi = ti - 4 + r, gj = tj - 4 + c;
      bufB[r * 41 + c] = (gi >= 0 && gi < n && gj >= 0 && gj < n) ? Q[(size_t)gi * n + gj] * H0SQ : 0.f;
    }
    __syncthreads();
    for (int t = lid; t < 23 * 23; t += NT) {
      int r = t / 23, c = t - r * 23;
      float v = 0.f;
      if ((c0i + r) >= 1 && (c0i + r) < N1 - 1 && (c0j + c) >= 1 && (c0j + c) < N1 - 1)
        v = C1F * (-C1F * (sq1[r * 26 + c + 1] + sq1[(r + 2) * 26 + c + 1] +
                           sq1[(r + 1) * 26 + c] + sq1[(r + 1) * 26 + c + 2])
                   - sq1[(r + 1) * 26 + c + 1]);
      sp1[r * 24 + c] = v;
    }
    __syncthreads();
    for (int t = lid; t < 42 * 42; t += NT) {
      int r = t / 42, c = t - r * 42;
      int gi = ti - 5 + r, gj = tj - 5 + c;
      float v = 0.f;
      if (gi >= 0 && gi < n && gj >= 0 && gj < n) {
        int r1 = (gi >> 1) - c0i, c1 = (gj >> 1) - c0j;
        float a = sp1[r1 * 24 + c1],       b = sp1[r1 * 24 + c1 + 1];
        float e = sp1[(r1 + 1) * 24 + c1], d = sp1[(r1 + 1) * 24 + c1 + 1];
        float wx = (gj & 1) ? 0.5f : 0.f, wy = (gi & 1) ? 0.5f : 0.f;
        float r0 = a + wx * (b - a), rr = e + wx * (d - e);
        // pA/pB boundary is 0 by construction; index 512 is unwritten -> read as 0
        float pv = (gi >= 1 && gi < n - 1 && gj >= 1 && gj < n - 1)
                   ? P[(size_t)gi * n + gj] : 0.f;
        v = pv + (r0 + wy * (rr - r0));
      }
      bufA[r * 43 + c] = v;
    }
    __syncthreads();
  }
}

// ------------------------------------------------------------------- vleg ---
template<bool INT>
__device__ __forceinline__ void vleg_body(
    const float* __restrict__ P, const float* __restrict__ Q,
    const float* __restrict__ q1, float* __restrict__ outp, float* __restrict__ q1o,
    int ti, int tj, int c0i, int c0j, int ic0, int jc0,
    size_t base, size_t cbase, int lid,
    float* __restrict__ bufA, float* __restrict__ bufB,
    float* __restrict__ bufC, float* __restrict__ bufD) {
  const int n = N0;
  coarse_and_v<INT>(P, Q, q1, ti, tj, c0i, c0j, lid, bufA, bufB, bufD, bufD + 25 * 26);
  if constexpr (INT) {
    sweep_v<40, 40, 43, 41, 41, false>(bufA, bufB, bufC, lid);         // s1
    __syncthreads();
    sweep_v<38, 38, 41, 41, 39, false>(bufC, bufB + 42, bufD, lid);    // s2
    __syncthreads();
    sweep_v<36, 36, 39, 41, 37, false>(bufD, bufB + 84, bufA, lid);    // s3
    __syncthreads();
    sweep_v_store<37, 41, 35>(bufA, bufB + 126, bufC, outp + base, ti, tj, lid);
    __syncthreads();
  } else {
    for (int t = lid; t < 40 * 40; t += NT) {   // s1
      int r = t / 40, c = t - r * 40;
      float v = 0.f;
      if ((ti - 4 + r) >= 1 && (ti - 4 + r) < n - 1 && (tj - 4 + c) >= 1 && (tj - 4 + c) < n - 1)
        v = C0F * (bufA[r * 43 + c + 1] + bufA[(r + 2) * 43 + c + 1] +
                   bufA[(r + 1) * 43 + c] + bufA[(r + 1) * 43 + c + 2] - bufB[r * 41 + c]);
      bufC[r * 41 + c] = v;
    }
    __syncthreads();
    for (int t = lid; t < 38 * 38; t += NT) {   // s2
      int r = t / 38, c = t - r * 38;
      float v = 0.f;
      if ((ti - 3 + r) >= 1 && (ti - 3 + r) < n - 1 && (tj - 3 + c) >= 1 && (tj - 3 + c) < n - 1)
        v = C0F * (bufC[r * 41 + c + 1] + bufC[(r + 2) * 41 + c + 1] +
                   bufC[(r + 1) * 41 + c] + bufC[(r + 1) * 41 + c + 2] - bufB[(r + 1) * 41 + c + 1]);
      bufD[r * 39 + c] = v;
    }
    __syncthreads();
    for (int t = lid; t < 36 * 36; t += NT) {   // s3
      int r = t / 36, c = t - r * 36;
      float v = 0.f;
      if ((ti - 2 + r) >= 1 && (ti - 2 + r) < n - 1 && (tj - 2 + c) >= 1 && (tj - 2 + c) < n - 1)
        v = C0F * (bufD[r * 39 + c + 1] + bufD[(r + 2) * 39 + c + 1] +
                   bufD[(r + 1) * 39 + c] + bufD[(r + 1) * 39 + c + 2] - bufB[(r + 2) * 41 + c + 2]);
      bufA[r * 37 + c] = v;
    }
    __syncthreads();
    for (int t = lid; t < 34 * 34; t += NT) {   // s4 + store
      int r = t / 34, c = t - r * 34;
      float v = 0.f;
      if ((ti - 1 + r) >= 1 && (ti - 1 + r) < n - 1 && (tj - 1 + c) >= 1 && (tj - 1 + c) < n - 1)
        v = C0F * (bufA[r * 37 + c + 1] + bufA[(r + 2) * 37 + c + 1] +
                   bufA[(r + 1) * 37 + c] + bufA[(r + 1) * 37 + c + 2] - bufB[(r + 3) * 41 + c + 3]);
      bufC[r * 35 + c] = v;
      if (r >= 1 && r <= 32 && c >= 1 && c <= 32 && (ti - 1 + r) < n && (tj - 1 + c) < n)
        outp[base + (size_t)(ti - 1 + r) * n + (tj - 1 + c)] = v;
    }
    __syncthreads();
  }
  if (lid < 256) {
    int cy = lid >> 4, cx = lid & 15;
    int ic = ic0 + cy, jc = jc0 + cx;
    if (INT || (ic < N1 && jc < N1)) {
      float v = 0.f;
      if (INT || (ic >= 1 && ic < N1 - 1 && jc >= 1 && jc < N1 - 1)) {
        int r = 2 * cy + 1, c = 2 * cx + 1;
        v = 4.f * (D0F * bufC[r * 35 + c] - bufC[(r - 1) * 35 + c] - bufC[(r + 1) * 35 + c]
                   - bufC[r * 35 + c - 1] - bufC[r * 35 + c + 1]
                   + bufB[(2 * cy + 4) * 41 + 2 * cx + 4]);
      }
      q1o[cbase + (size_t)ic * N1 + jc] = v;
    }
  }
}

__global__ __launch_bounds__(NT) void vleg_k(
    const float* __restrict__ psi, const float* __restrict__ Qg,
    const float* __restrict__ q1g, float* __restrict__ out, float* __restrict__ q1o) {
  __shared__ float bufA[42 * 43];
  __shared__ float bufB[40 * 41];
  __shared__ float bufC[40 * 41];
  __shared__ float bufD[38 * 39];
  int bx = blockIdx.x, by = blockIdx.y;
  int ti = by * 32, tj = bx * 32;
  int c0i = 16 * by - 3, c0j = 16 * bx - 3;
  size_t base = (size_t)blockIdx.z * (N0 * N0);
  size_t cbase = (size_t)blockIdx.z * (N1 * N1);
  const float* q1 = q1g + cbase;
  int lid = threadIdx.y * 32 + threadIdx.x;
  bool inter = (bx >= 1 && bx <= 14 && by >= 1 && by <= 14);
  if (inter)
    vleg_body<true>(psi + base, Qg + base, q1, out, q1o, ti, tj, c0i, c0j,
                    16 * by, 16 * bx, base, cbase, lid, bufA, bufB, bufC, bufD);
  else
    vleg_body<false>(psi + base, Qg + base, q1, out, q1o, ti, tj, c0i, c0j,
                     16 * by, 16 * bx, base, cbase, lid, bufA, bufB, bufC, bufD);
}

// ------------------------------------------------------------------- mega ---
template<bool INT>
__device__ __forceinline__ void mega_body(
    const float* __restrict__ P, const float* __restrict__ Q,
    const float* __restrict__ q1, const float* __restrict__ CT,
    float* __restrict__ psi_out, float* __restrict__ qf_out,
    int ti, int tj, int c0i, int c0j, size_t base, int lid,
    float* __restrict__ bufA, float* __restrict__ bufB,
    float* __restrict__ bufC, float* __restrict__ bufD) {
  const int n = N0;
  coarse_and_v<INT>(P, Q, q1, ti, tj, c0i, c0j, lid, bufA, bufB, bufD, bufD + 25 * 26);
  if constexpr (INT) {
    sweep_v<40, 40, 43, 41, 41, false>(bufA, bufB, bufC, lid);         // s1
    __syncthreads();
    sweep_v<38, 38, 41, 41, 39, false>(bufC, bufB + 42, bufD, lid);    // s2
    __syncthreads();
    sweep_v<36, 36, 39, 41, 37, true>(bufD, bufB, bufA, lid);          // Z
    __syncthreads();
    sweep_v<34, 34, 37, 41, 35, true>(bufA, bufB, bufC, lid);          // Z2
    __syncthreads();
    // 2-row-strip epilogue with register-shared rows
    {
      int tx = lid & 31, rb = lid >> 5;
      int y0 = 2 * rb;
      int i0 = ti + y0, j = tj + tx;
      size_t idx0 = base + (size_t)i0 * n + j;
      const float* dp = bufD + (y0 + 2) * 39 + tx + 2;   // rows y0+2..y0+5
      float A0 = dp[0],   A1 = dp[1],   A2 = dp[2];
      float B0 = dp[39],  B1 = dp[40],  B2 = dp[41];
      float C0 = dp[78],  C1 = dp[79],  C2 = dp[80];
      float D0 = dp[117], D1 = dp[118], D2 = dp[119];
      const float* qp = bufB + (y0 + 3) * 41 + tx + 3;   // rows y0+3..y0+6
      float q00 = qp[0],   q01 = qp[1],   q02 = qp[2];
      float q10 = qp[41],  q11 = qp[42],  q12 = qp[43];
      float q20 = qp[82],  q21 = qp[83],  q22 = qp[84];
      float q30 = qp[123], q31 = qp[124], q32 = qp[125];
      const float* ap = bufA + (y0 + 2) * 37 + tx + 2;
      float z1a = ap[0], z1b = ap[37];
      const float* cp = bufC + y0 * 35 + tx + 1;         // center col + sides
      float zc0 = cp[0], zc1 = cp[35], zc2 = cp[70], zc3 = cp[105];
      float sWa = cp[34], sEa = cp[36];
      float sWb = cp[69], sEb = cp[71];
      psi_out[idx0]     = B1;
      psi_out[idx0 + n] = C1;
      float z4a = (sWa + sEa + zc0 + zc2) * INV_DX2 - zc1 * CENTER;
      float z4b = (sWb + sEb + zc1 + zc3) * INV_DX2 - zc2 * CENTER;
      float J0 = (B0 - A1) * q00
               + (A0 + B0 - A2 - B2) * q01
               + (A1 - B2) * q02
               + (C0 + C1 - A0 - A1) * q10
               + (A1 + A2 - C1 - C2) * q12
               + (C1 - B0) * q20
               + (B2 + C2 - B0 - C0) * q21
               + (B2 - C1) * q22;
      J0 *= INV12S;
      float J1 = (C0 - B1) * q10
               + (B0 + C0 - B2 - C2) * q11
               + (B1 - C2) * q12
               + (D0 + D1 - B0 - B1) * q20
               + (B1 + B2 - D1 - D2) * q22
               + (D1 - C0) * q30
               + (C2 + D2 - C0 - D0) * q31
               + (C2 - D1) * q32;
      J1 *= INV12S;
      float ct0 = CT[(size_t)i0 * n + j];
      float ct1 = CT[(size_t)(i0 + 1) * n + j];
      qf_out[idx0]     = -J0 - 1e-6f * z1a + 1e-8f * zc1 - 2e-11f * z4a + ct0
                         - 256.0f * (B2 - B0);
      qf_out[idx0 + n] = -J1 - 1e-6f * z1b + 1e-8f * zc2 - 2e-11f * z4b + ct1
                         - 256.0f * (C2 - C0);
    }
  } else {
    for (int t = lid; t < 40 * 40; t += NT) {   // s1
      int r = t / 40, c = t - r * 40;
      float v = 0.f;
      if ((ti - 4 + r) >= 1 && (ti - 4 + r) < n - 1 && (tj - 4 + c) >= 1 && (tj - 4 + c) < n - 1)
        v = C0F * (bufA[r * 43 + c + 1] + bufA[(r + 2) * 43 + c + 1] +
                   bufA[(r + 1) * 43 + c] + bufA[(r + 1) * 43 + c + 2] - bufB[r * 41 + c]);
      bufC[r * 41 + c] = v;
    }
    __syncthreads();
    for (int t = lid; t < 38 * 38; t += NT) {   // s2
      int r = t / 38, c = t - r * 38;
      float v = 0.f;
      if ((ti - 3 + r) >= 1 && (ti - 3 + r) < n - 1 && (tj - 3 + c) >= 1 && (tj - 3 + c) < n - 1)
        v = C0F * (bufC[r * 41 + c + 1] + bufC[(r + 2) * 41 + c + 1] +
                   bufC[(r + 1) * 41 + c] + bufC[(r + 1) * 41 + c + 2] - bufB[(r + 1) * 41 + c + 1]);
      bufD[r * 39 + c] = v;
    }
    __syncthreads();
    for (int t = lid; t < 36 * 36; t += NT) {   // Z
      int r = t / 36, c = t - r * 36;
      float v = 0.f;
      if ((ti - 2 + r) >= 1 && (ti - 2 + r) < n - 1 && (tj - 2 + c) >= 1 && (tj - 2 + c) < n - 1)
        v = (bufD[r * 39 + c + 1] + bufD[(r + 2) * 39 + c + 1] +
             bufD[(r + 1) * 39 + c] + bufD[(r + 1) * 39 + c + 2]) * INV_DX2
            - bufD[(r + 1) * 39 + c + 1] * CENTER;
      bufA[r * 37 + c] = v;
    }
    __syncthreads();
    for (int t = lid; t < 34 * 34; t += NT) {   // Z2
      int r = t / 34, c = t - r * 34;
      float v = 0.f;
      if ((ti - 1 + r) >= 1 && (ti - 1 + r) < n - 1 && (tj - 1 + c) >= 1 && (tj - 1 + c) < n - 1)
        v = (bufA[r * 37 + c + 1] + bufA[(r + 2) * 37 + c + 1] +
             bufA[(r + 1) * 37 + c] + bufA[(r + 1) * 37 + c + 2]) * INV_DX2
            - bufA[(r + 1) * 37 + c + 1] * CENTER;
      bufC[r * 35 + c] = v;
    }
    __syncthreads();
    int tx = lid & 31, ty = lid >> 5;
    #pragma unroll
    for (int s = 0; s < 2; s++) {
      int yy = ty + 16 * s;
      int i = ti + yy, j = tj + tx;
      if (i >= n || j >= n) continue;
      size_t idx = base + (size_t)i * n + j;
      int pr = yy + 3, pc = tx + 3;
      psi_out[idx] = bufD[pr * 39 + pc];
      float qv = 0.f;
      if (i >= 1 && i < n - 1 && j >= 1 && j < n - 1) {
        float z1v = bufA[(yy + 2) * 37 + tx + 2];
        int r2 = yy + 1, c2 = tx + 1;
        float z2v = bufC[r2 * 35 + c2];
        float z4 = (bufC[r2 * 35 + c2 - 1] + bufC[r2 * 35 + c2 + 1] +
                    bufC[(r2 - 1) * 35 + c2] + bufC[(r2 + 1) * 35 + c2]) * INV_DX2
                   - z2v * CENTER;
        float Amm = bufD[(pr - 1) * 39 + pc - 1], Am0 = bufD[(pr - 1) * 39 + pc],
              Amp = bufD[(pr - 1) * 39 + pc + 1];
        float A0m = bufD[pr * 39 + pc - 1], A0p = bufD[pr * 39 + pc + 1];
        float Apm = bufD[(pr + 1) * 39 + pc - 1], Ap0 = bufD[(pr + 1) * 39 + pc],
              App = bufD[(pr + 1) * 39 + pc + 1];
        int qr = yy + 4, qc = tx + 4;
        float J = (A0m - Am0) * bufB[(qr - 1) * 41 + qc - 1]
                + (Amm + A0m - Amp - A0p) * bufB[(qr - 1) * 41 + qc]
                + (Am0 - A0p) * bufB[(qr - 1) * 41 + qc + 1]
                + (Apm + Ap0 - Amm - Am0) * bufB[qr * 41 + qc - 1]
                + (Am0 + Amp - Ap0 - App) * bufB[qr * 41 + qc + 1]
                + (Ap0 - A0m) * bufB[(qr + 1) * 41 + qc - 1]
                + (A0p + App - A0m - Apm) * bufB[(qr + 1) * 41 + qc]
                + (A0p - Ap0) * bufB[(qr + 1) * 41 + qc + 1];
        J *= INV12S;
        float ct = CT[(size_t)i * n + j];
        qv = -J - 1e-6f * z1v + 1e-8f * z2v - 2e-11f * z4 + ct - 256.0f * (A0p - A0m);
      }
      qf_out[idx] = qv;
    }
  }
}

__global__ __launch_bounds__(NT) void mega_k(
    const float* __restrict__ psi, const float* __restrict__ Qg,
    const float* __restrict__ q1g, const float* __restrict__ CT,
    float* __restrict__ psi_out, float* __restrict__ qf_out) {
  __shared__ float bufA[42 * 43];
  __shared__ float bufB[40 * 41];
  __shared__ float bufC[40 * 41];
  __shared__ float bufD[38 * 39];
  int bx = blockIdx.x, by = blockIdx.y;
  int ti = by * 32, tj = bx * 32;
  int c0i = 16 * by - 3, c0j = 16 * bx - 3;
  size_t base = (size_t)blockIdx.z * (N0 * N0);
  const float* q1 = q1g + (size_t)blockIdx.z * (N1 * N1);
  int lid = threadIdx.y * 32 + threadIdx.x;
  bool inter = (bx >= 1 && bx <= 14 && by >= 1 && by <= 14);
  if (inter)
    mega_body<true>(psi + base, Qg + base, q1, CT, psi_out, qf_out,
                    ti, tj, c0i, c0j, base, lid, bufA, bufB, bufC, bufD);
  else
    mega_body<false>(psi + base, Qg + base, q1, CT, psi_out, qf_out,
                     ti, tj, c0i, c0j, base, lid, bufA, bufB, bufC, bufD);
}

extern "C" void kernel_launch(void* const* d_in, const int* in_sizes, int n_in,
                              void* d_out, int out_size, void* d_ws, size_t ws_size,
                              hipStream_t stream) {
  const float* PSIG = (const float*)d_in[1];
  const float* Q    = (const float*)d_in[2];
  const float* CT   = (const float*)d_in[3];

  float* ws = (float*)d_ws;
  size_t f0 = (size_t)NB * N0 * N0;
  size_t f1 = (size_t)NB * N1 * N1;
  float* pA  = ws;
  float* pB  = pA + f0;
  float* q1a = pB + f0;
  float* q1b = q1a + f1;

  float* psi_out = (float*)d_out;
  float* qf_out  = psi_out + f0;

  dim3 blk(32, 16, 1), grd(16, 16, NB);

  zfill_k<<<dim3(NB), dim3(256), 0, stream>>>(psi_out, qf_out);
  drelaxR_k<<<grd, blk, 0, stream>>>(PSIG, Q, pA, q1a);      // cycle-1 down
  vleg_k<<<grd, blk, 0, stream>>>(pA, Q, q1a, pB, q1b);      // c1 up + c2 down
  mega_k<<<grd, blk, 0, stream>>>(pB, Q, q1b, CT, psi_out, qf_out);  // c2 up + flux
}

// Round 13
// 100.798 us; speedup vs baseline: 1.0861x; 1.0861x over previous
//
#include <hip/hip_runtime.h>

// qg_flux, round 13: REVERT to round-11 (best: ~100.7 µs). r12's sliver-block
// elimination regressed (load imbalance + serial zfill). This is the r11
// source verbatim: 17x17 grid, 512-thread blocks, vertical 4-row-strip stage
// loops, register-shared 2-row epilogue, prolong row-chain, edge template.

#define N0 513
#define N1 257
#define NB 16
#define NT 512

#define C0F ((float)(1.0 / 4.006103515625))
#define D0F 4.006103515625f
#define C1F ((float)(1.0 / 4.0244140625))
#define H0SQ 3.814697265625e-06f            // h0^2 = 2^-18, exact
#define INV_DX2 262144.0f                   // 2^18
#define CENTER  1048576.0f                  // 4*2^18
#define INV12S  ((float)(262144.0 / 12.0 * 262144.0))  // INV12 * 2^18

// ---- vertical-strip helpers (interior blocks only; no bounds checks) -------

template<int W, int H, int SL, int GS, bool SC>
__device__ __forceinline__ void stage_v(const float* __restrict__ g,
                                        int oi, int oj,
                                        float* __restrict__ s, int lid) {
  constexpr int RB = (H + 3) / 4;
  if (lid < W * RB) {
    int c = lid % W, rb = lid / W, r0 = rb * 4;
    const float* gp = g + (size_t)(oi + r0) * GS + (oj + c);
    #pragma unroll
    for (int k = 0; k < 4; k++) {
      if constexpr (H % 4 != 0) { if (r0 + k >= H) break; }
      float v = gp[k * GS];
      s[(r0 + k) * SL + c] = SC ? v * H0SQ : v;
    }
  }
}

template<int W, int H, int SI, int SQ, int SO, bool LAP>
__device__ __forceinline__ void sweep_v(const float* __restrict__ in,
                                        const float* __restrict__ qq,
                                        float* __restrict__ out, int lid) {
  constexpr int RB = (H + 3) / 4;
  if (lid < W * RB) {
    int c = lid % W, rb = lid / W, r0 = rb * 4;
    const float* colp = in + r0 * SI + (c + 1);
    float vn = colp[0];
    float vc = colp[SI];
    #pragma unroll
    for (int k = 0; k < 4; k++) {
      if constexpr (H % 4 != 0) { if (r0 + k >= H) break; }
      int r = r0 + k;
      float vs = colp[(k + 2) * SI];
      float wv = in[(r + 1) * SI + c];
      float ev = in[(r + 1) * SI + c + 2];
      float o;
      if constexpr (LAP)
        o = (vn + vs + wv + ev) * INV_DX2 - vc * CENTER;
      else
        o = C0F * (vn + vs + wv + ev - qq[r * SQ + c]);
      out[r * SO + c] = o;
      vn = vc; vc = vs;
    }
  }
}

template<int SI, int SQ, int SO>
__device__ __forceinline__ void sweep_v_store(const float* __restrict__ in,
                                              const float* __restrict__ qq,
                                              float* __restrict__ out,
                                              float* __restrict__ gout,
                                              int ti, int tj, int lid) {
  constexpr int W = 34, H = 34, RB = 9;
  if (lid < W * RB) {
    int c = lid % W, rb = lid / W, r0 = rb * 4;
    const float* colp = in + r0 * SI + (c + 1);
    float vn = colp[0];
    float vc = colp[SI];
    bool cin = (c >= 1 && c <= 32);
    #pragma unroll
    for (int k = 0; k < 4; k++) {
      if (r0 + k >= H) break;
      int r = r0 + k;
      float vs = colp[(k + 2) * SI];
      float wv = in[(r + 1) * SI + c];
      float ev = in[(r + 1) * SI + c + 2];
      float o = C0F * (vn + vs + wv + ev - qq[r * SQ + c]);
      out[r * SO + c] = o;
      if (cin && r >= 1 && r <= 32)
        gout[(size_t)(ti - 1 + r) * N0 + (tj - 1 + c)] = o;
      vn = vc; vc = vs;
    }
  }
}

// prolong with row-chain: gi0 = ti-5+r0 is ODD (ti = 32*by), so the 4-row
// strip needs coarse rows m..m+2 only; wy alternates {1/2, 0, 1/2, 0}.
__device__ __forceinline__ void prolong_v(const float* __restrict__ P,
                                          const float* __restrict__ sp1,
                                          float* __restrict__ bufA,
                                          int ti, int tj, int c0i, int c0j,
                                          int lid) {
  constexpr int W = 42, RB = 11;
  if (lid < W * RB) {
    int c = lid % W, rb = lid / W, r0 = rb * 4;
    int gj = tj - 5 + c;
    int c1 = (gj >> 1) - c0j;
    float wx = (gj & 1) ? 0.5f : 0.f;
    const float* gp = P + (size_t)(ti - 5 + r0) * N0 + gj;
    int m = (ti - 5 + r0) >> 1;
    const float* s0 = sp1 + (m - c0i) * 24 + c1;
    float a0 = s0[0],  b0 = s0[1];
    float a1 = s0[24], b1 = s0[25];
    float t0 = a0 + wx * (b0 - a0);
    float t1 = a1 + wx * (b1 - a1);
    bufA[r0 * 43 + c]       = gp[0]  + (t0 + 0.5f * (t1 - t0));  // gi odd
    bufA[(r0 + 1) * 43 + c] = gp[N0] + (t1 + 0.f);               // gi even
    if (r0 + 2 < 42) {
      float a2 = s0[48], b2 = s0[49];
      float t2 = a2 + wx * (b2 - a2);
      bufA[(r0 + 2) * 43 + c] = gp[2 * N0] + (t1 + 0.5f * (t2 - t1));
      bufA[(r0 + 3) * 43 + c] = gp[3 * N0] + (t2 + 0.f);
    }
  }
}

// ---------------------------------------------------------------- drelaxR ---
template<bool INT>
__device__ __forceinline__ void drelaxR_body(
    const float* __restrict__ P, const float* __restrict__ Q,
    float* __restrict__ outp, float* __restrict__ q1p,
    int ti, int tj, int ic0, int jc0, size_t base, size_t cbase, int lid,
    float* __restrict__ sIn, float* __restrict__ sQ,
    float* __restrict__ sT, float* __restrict__ sP) {
  const int n = N0;
  if constexpr (INT) {
    stage_v<38, 38, 39, N0, false>(P, ti - 3, tj - 3, sIn, lid);
    stage_v<36, 36, 37, N0, true>(Q, ti - 2, tj - 2, sQ, lid);
    __syncthreads();
    sweep_v<36, 36, 39, 37, 37, false>(sIn, sQ, sT, lid);
    __syncthreads();
    sweep_v_store<37, 37, 35>(sT, sQ + 38, sP, outp + base, ti, tj, lid);
    __syncthreads();
  } else {
    for (int t = lid; t < 38 * 38; t += NT) {
      int r = t / 38, c = t - r * 38;
      int gi = ti - 3 + r, gj = tj - 3 + c;
      sIn[r * 39 + c] = (gi >= 0 && gi < n && gj >= 0 && gj < n) ? P[(size_t)gi * n + gj] : 0.f;
    }
    for (int t = lid; t < 36 * 36; t += NT) {
      int r = t / 36, c = t - r * 36;
      int gi = ti - 2 + r, gj = tj - 2 + c;
      sQ[r * 37 + c] = (gi >= 0 && gi < n && gj >= 0 && gj < n) ? Q[(size_t)gi * n + gj] * H0SQ : 0.f;
    }
    __syncthreads();
    for (int t = lid; t < 36 * 36; t += NT) {
      int r = t / 36, c = t - r * 36;
      float v = 0.f;
      if ((ti - 2 + r) >= 1 && (ti - 2 + r) < n - 1 && (tj - 2 + c) >= 1 && (tj - 2 + c) < n - 1)
        v = C0F * (sIn[r * 39 + c + 1] + sIn[(r + 2) * 39 + c + 1] +
                   sIn[(r + 1) * 39 + c] + sIn[(r + 1) * 39 + c + 2] - sQ[r * 37 + c]);
      sT[r * 37 + c] = v;
    }
    __syncthreads();
    for (int t = lid; t < 34 * 34; t += NT) {
      int r = t / 34, c = t - r * 34;
      float v = 0.f;
      if ((ti - 1 + r) >= 1 && (ti - 1 + r) < n - 1 && (tj - 1 + c) >= 1 && (tj - 1 + c) < n - 1)
        v = C0F * (sT[r * 37 + c + 1] + sT[(r + 2) * 37 + c + 1] +
                   sT[(r + 1) * 37 + c] + sT[(r + 1) * 37 + c + 2] - sQ[(r + 1) * 37 + c + 1]);
      sP[r * 35 + c] = v;
      if (r >= 1 && r <= 32 && c >= 1 && c <= 32 && (ti - 1 + r) < n && (tj - 1 + c) < n)
        outp[base + (size_t)(ti - 1 + r) * n + (tj - 1 + c)] = v;
    }
    __syncthreads();
  }
  if (lid < 256) {
    int cy = lid >> 4, cx = lid & 15;
    int ic = ic0 + cy, jc = jc0 + cx;
    if (INT || (ic < N1 && jc < N1)) {
      float v = 0.f;
      if (INT || (ic >= 1 && ic < N1 - 1 && jc >= 1 && jc < N1 - 1)) {
        int r = 2 * cy + 1, c = 2 * cx + 1;
        v = 4.f * (D0F * sP[r * 35 + c] - sP[(r - 1) * 35 + c] - sP[(r + 1) * 35 + c]
                   - sP[r * 35 + c - 1] - sP[r * 35 + c + 1] + sQ[(r + 1) * 37 + c + 1]);
      }
      q1p[cbase + (size_t)ic * N1 + jc] = v;
    }
  }
}

__global__ __launch_bounds__(NT) void drelaxR_k(
    const float* __restrict__ psi, const float* __restrict__ Qg,
    float* __restrict__ out, float* __restrict__ q1) {
  __shared__ float smem[38 * 39 + 36 * 37 + 36 * 37];
  float* sIn = smem;
  float* sQ  = smem + 38 * 39;
  float* sT  = sQ + 36 * 37;
  float* sP  = smem;               // alias sIn (dead after s1)
  int bx = blockIdx.x, by = blockIdx.y;
  int ti = by * 32, tj = bx * 32;
  size_t base = (size_t)blockIdx.z * (N0 * N0);
  size_t cbase = (size_t)blockIdx.z * (N1 * N1);
  int lid = threadIdx.y * 32 + threadIdx.x;
  bool inter = (bx >= 1 && bx <= 14 && by >= 1 && by <= 14);
  if (inter)
    drelaxR_body<true>(psi + base, Qg + base, out, q1, ti, tj, 16 * by, 16 * bx,
                       base, cbase, lid, sIn, sQ, sT, sP);
  else
    drelaxR_body<false>(psi + base, Qg + base, out, q1, ti, tj, 16 * by, 16 * bx,
                        base, cbase, lid, sIn, sQ, sT, sP);
}

// ------------------------------------------------------- shared coarse prep --
template<bool INT>
__device__ __forceinline__ void coarse_and_v(
    const float* __restrict__ P, const float* __restrict__ Q,
    const float* __restrict__ q1,
    int ti, int tj, int c0i, int c0j, int lid,
    float* __restrict__ bufA, float* __restrict__ bufB,
    float* __restrict__ sq1, float* __restrict__ sp1) {
  const int n = N0;
  if constexpr (INT) {
    stage_v<25, 25, 26, N1, false>(q1, c0i - 1, c0j - 1, sq1, lid);
    stage_v<40, 40, 41, N0, true>(Q, ti - 4, tj - 4, bufB, lid);
    __syncthreads();
    // p1 strip-chained: 23x23 5-pt on sq1
    {
      constexpr int W = 23, RB = 6;
      if (lid < W * RB) {
        int c = lid % W, rb = lid / W, r0 = rb * 4;
        const float* colp = sq1 + r0 * 26 + (c + 1);
        float vn = colp[0];
        float vc = colp[26];
        #pragma unroll
        for (int k = 0; k < 4; k++) {
          if (r0 + k >= 23) break;
          int r = r0 + k;
          float vs = colp[(k + 2) * 26];
          float wv = sq1[(r + 1) * 26 + c];
          float ev = sq1[(r + 1) * 26 + c + 2];
          sp1[r * 24 + c] = C1F * (-C1F * (vn + vs + wv + ev) - vc);
          vn = vc; vc = vs;
        }
      }
    }
    __syncthreads();
    prolong_v(P, sp1, bufA, ti, tj, c0i, c0j, lid);
    __syncthreads();
  } else {
    for (int t = lid; t < 25 * 25; t += NT) {
      int r = t / 25, c = t - r * 25;
      int ci = c0i - 1 + r, cj = c0j - 1 + c;
      sq1[r * 26 + c] = (ci >= 0 && ci < N1 && cj >= 0 && cj < N1) ? q1[(size_t)ci * N1 + cj] : 0.f;
    }
    for (int t = lid; t < 40 * 40; t += NT) {
      int r = t / 40, c = t - r * 40;
      int gi = ti - 4 + r, gj = tj - 4 + c;
      bufB[r * 41 + c] = (gi >= 0 && gi < n && gj >= 0 && gj < n) ? Q[(size_t)gi * n + gj] * H0SQ : 0.f;
    }
    __syncthreads();
    for (int t = lid; t < 23 * 23; t += NT) {
      int r = t / 23, c = t - r * 23;
      float v = 0.f;
      if ((c0i + r) >= 1 && (c0i + r) < N1 - 1 && (c0j + c) >= 1 && (c0j + c) < N1 - 1)
        v = C1F * (-C1F * (sq1[r * 26 + c + 1] + sq1[(r + 2) * 26 + c + 1] +
                           sq1[(r + 1) * 26 + c] + sq1[(r + 1) * 26 + c + 2])
                   - sq1[(r + 1) * 26 + c + 1]);
      sp1[r * 24 + c] = v;
    }
    __syncthreads();
    for (int t = lid; t < 42 * 42; t += NT) {
      int r = t / 42, c = t - r * 42;
      int gi = ti - 5 + r, gj = tj - 5 + c;
      float v = 0.f;
      if (gi >= 0 && gi < n && gj >= 0 && gj < n) {
        int r1 = (gi >> 1) - c0i, c1 = (gj >> 1) - c0j;
        float a = sp1[r1 * 24 + c1],       b = sp1[r1 * 24 + c1 + 1];
        float e = sp1[(r1 + 1) * 24 + c1], d = sp1[(r1 + 1) * 24 + c1 + 1];
        float wx = (gj & 1) ? 0.5f : 0.f, wy = (gi & 1) ? 0.5f : 0.f;
        float r0 = a + wx * (b - a), rr = e + wx * (d - e);
        v = P[(size_t)gi * n + gj] + (r0 + wy * (rr - r0));
      }
      bufA[r * 43 + c] = v;
    }
    __syncthreads();
  }
}

// ------------------------------------------------------------------- vleg ---
template<bool INT>
__device__ __forceinline__ void vleg_body(
    const float* __restrict__ P, const float* __restrict__ Q,
    const float* __restrict__ q1, float* __restrict__ outp, float* __restrict__ q1o,
    int ti, int tj, int c0i, int c0j, int ic0, int jc0,
    size_t base, size_t cbase, int lid,
    float* __restrict__ bufA, float* __restrict__ bufB,
    float* __restrict__ bufC, float* __restrict__ bufD) {
  const int n = N0;
  coarse_and_v<INT>(P, Q, q1, ti, tj, c0i, c0j, lid, bufA, bufB, bufD, bufD + 25 * 26);
  if constexpr (INT) {
    sweep_v<40, 40, 43, 41, 41, false>(bufA, bufB, bufC, lid);         // s1
    __syncthreads();
    sweep_v<38, 38, 41, 41, 39, false>(bufC, bufB + 42, bufD, lid);    // s2
    __syncthreads();
    sweep_v<36, 36, 39, 41, 37, false>(bufD, bufB + 84, bufA, lid);    // s3
    __syncthreads();
    sweep_v_store<37, 41, 35>(bufA, bufB + 126, bufC, outp + base, ti, tj, lid);
    __syncthreads();
  } else {
    for (int t = lid; t < 40 * 40; t += NT) {   // s1
      int r = t / 40, c = t - r * 40;
      float v = 0.f;
      if ((ti - 4 + r) >= 1 && (ti - 4 + r) < n - 1 && (tj - 4 + c) >= 1 && (tj - 4 + c) < n - 1)
        v = C0F * (bufA[r * 43 + c + 1] + bufA[(r + 2) * 43 + c + 1] +
                   bufA[(r + 1) * 43 + c] + bufA[(r + 1) * 43 + c + 2] - bufB[r * 41 + c]);
      bufC[r * 41 + c] = v;
    }
    __syncthreads();
    for (int t = lid; t < 38 * 38; t += NT) {   // s2
      int r = t / 38, c = t - r * 38;
      float v = 0.f;
      if ((ti - 3 + r) >= 1 && (ti - 3 + r) < n - 1 && (tj - 3 + c) >= 1 && (tj - 3 + c) < n - 1)
        v = C0F * (bufC[r * 41 + c + 1] + bufC[(r + 2) * 41 + c + 1] +
                   bufC[(r + 1) * 41 + c] + bufC[(r + 1) * 41 + c + 2] - bufB[(r + 1) * 41 + c + 1]);
      bufD[r * 39 + c] = v;
    }
    __syncthreads();
    for (int t = lid; t < 36 * 36; t += NT) {   // s3
      int r = t / 36, c = t - r * 36;
      float v = 0.f;
      if ((ti - 2 + r) >= 1 && (ti - 2 + r) < n - 1 && (tj - 2 + c) >= 1 && (tj - 2 + c) < n - 1)
        v = C0F * (bufD[r * 39 + c + 1] + bufD[(r + 2) * 39 + c + 1] +
                   bufD[(r + 1) * 39 + c] + bufD[(r + 1) * 39 + c + 2] - bufB[(r + 2) * 41 + c + 2]);
      bufA[r * 37 + c] = v;
    }
    __syncthreads();
    for (int t = lid; t < 34 * 34; t += NT) {   // s4 + store
      int r = t / 34, c = t - r * 34;
      float v = 0.f;
      if ((ti - 1 + r) >= 1 && (ti - 1 + r) < n - 1 && (tj - 1 + c) >= 1 && (tj - 1 + c) < n - 1)
        v = C0F * (bufA[r * 37 + c + 1] + bufA[(r + 2) * 37 + c + 1] +
                   bufA[(r + 1) * 37 + c] + bufA[(r + 1) * 37 + c + 2] - bufB[(r + 3) * 41 + c + 3]);
      bufC[r * 35 + c] = v;
      if (r >= 1 && r <= 32 && c >= 1 && c <= 32 && (ti - 1 + r) < n && (tj - 1 + c) < n)
        outp[base + (size_t)(ti - 1 + r) * n + (tj - 1 + c)] = v;
    }
    __syncthreads();
  }
  if (lid < 256) {
    int cy = lid >> 4, cx = lid & 15;
    int ic = ic0 + cy, jc = jc0 + cx;
    if (INT || (ic < N1 && jc < N1)) {
      float v = 0.f;
      if (INT || (ic >= 1 && ic < N1 - 1 && jc >= 1 && jc < N1 - 1)) {
        int r = 2 * cy + 1, c = 2 * cx + 1;
        v = 4.f * (D0F * bufC[r * 35 + c] - bufC[(r - 1) * 35 + c] - bufC[(r + 1) * 35 + c]
                   - bufC[r * 35 + c - 1] - bufC[r * 35 + c + 1]
                   + bufB[(2 * cy + 4) * 41 + 2 * cx + 4]);
      }
      q1o[cbase + (size_t)ic * N1 + jc] = v;
    }
  }
}

__global__ __launch_bounds__(NT) void vleg_k(
    const float* __restrict__ psi, const float* __restrict__ Qg,
    const float* __restrict__ q1g, float* __restrict__ out, float* __restrict__ q1o) {
  __shared__ float bufA[42 * 43];
  __shared__ float bufB[40 * 41];
  __shared__ float bufC[40 * 41];
  __shared__ float bufD[38 * 39];
  int bx = blockIdx.x, by = blockIdx.y;
  int ti = by * 32, tj = bx * 32;
  int c0i = 16 * by - 3, c0j = 16 * bx - 3;
  size_t base = (size_t)blockIdx.z * (N0 * N0);
  size_t cbase = (size_t)blockIdx.z * (N1 * N1);
  const float* q1 = q1g + cbase;
  int lid = threadIdx.y * 32 + threadIdx.x;
  bool inter = (bx >= 1 && bx <= 14 && by >= 1 && by <= 14);
  if (inter)
    vleg_body<true>(psi + base, Qg + base, q1, out, q1o, ti, tj, c0i, c0j,
                    16 * by, 16 * bx, base, cbase, lid, bufA, bufB, bufC, bufD);
  else
    vleg_body<false>(psi + base, Qg + base, q1, out, q1o, ti, tj, c0i, c0j,
                     16 * by, 16 * bx, base, cbase, lid, bufA, bufB, bufC, bufD);
}

// ------------------------------------------------------------------- mega ---
template<bool INT>
__device__ __forceinline__ void mega_body(
    const float* __restrict__ P, const float* __restrict__ Q,
    const float* __restrict__ q1, const float* __restrict__ CT,
    float* __restrict__ psi_out, float* __restrict__ qf_out,
    int ti, int tj, int c0i, int c0j, size_t base, int lid,
    float* __restrict__ bufA, float* __restrict__ bufB,
    float* __restrict__ bufC, float* __restrict__ bufD) {
  const int n = N0;
  coarse_and_v<INT>(P, Q, q1, ti, tj, c0i, c0j, lid, bufA, bufB, bufD, bufD + 25 * 26);
  if constexpr (INT) {
    sweep_v<40, 40, 43, 41, 41, false>(bufA, bufB, bufC, lid);         // s1
    __syncthreads();
    sweep_v<38, 38, 41, 41, 39, false>(bufC, bufB + 42, bufD, lid);    // s2
    __syncthreads();
    sweep_v<36, 36, 39, 41, 37, true>(bufD, bufB, bufA, lid);          // Z
    __syncthreads();
    sweep_v<34, 34, 37, 41, 35, true>(bufA, bufB, bufC, lid);          // Z2
    __syncthreads();
    // 2-row-strip epilogue with register-shared rows
    {
      int tx = lid & 31, rb = lid >> 5;
      int y0 = 2 * rb;
      int i0 = ti + y0, j = tj + tx;
      size_t idx0 = base + (size_t)i0 * n + j;
      const float* dp = bufD + (y0 + 2) * 39 + tx + 2;   // rows y0+2..y0+5
      float A0 = dp[0],   A1 = dp[1],   A2 = dp[2];
      float B0 = dp[39],  B1 = dp[40],  B2 = dp[41];
      float C0 = dp[78],  C1 = dp[79],  C2 = dp[80];
      float D0 = dp[117], D1 = dp[118], D2 = dp[119];
      const float* qp = bufB + (y0 + 3) * 41 + tx + 3;   // rows y0+3..y0+6
      float q00 = qp[0],   q01 = qp[1],   q02 = qp[2];
      float q10 = qp[41],  q11 = qp[42],  q12 = qp[43];
      float q20 = qp[82],  q21 = qp[83],  q22 = qp[84];
      float q30 = qp[123], q31 = qp[124], q32 = qp[125];
      const float* ap = bufA + (y0 + 2) * 37 + tx + 2;
      float z1a = ap[0], z1b = ap[37];
      const float* cp = bufC + y0 * 35 + tx + 1;         // center col + sides
      float zc0 = cp[0], zc1 = cp[35], zc2 = cp[70], zc3 = cp[105];
      float sWa = cp[34], sEa = cp[36];
      float sWb = cp[69], sEb = cp[71];
      psi_out[idx0]     = B1;
      psi_out[idx0 + n] = C1;
      float z4a = (sWa + sEa + zc0 + zc2) * INV_DX2 - zc1 * CENTER;
      float z4b = (sWb + sEb + zc1 + zc3) * INV_DX2 - zc2 * CENTER;
      float J0 = (B0 - A1) * q00
               + (A0 + B0 - A2 - B2) * q01
               + (A1 - B2) * q02
               + (C0 + C1 - A0 - A1) * q10
               + (A1 + A2 - C1 - C2) * q12
               + (C1 - B0) * q20
               + (B2 + C2 - B0 - C0) * q21
               + (B2 - C1) * q22;
      J0 *= INV12S;
      float J1 = (C0 - B1) * q10
               + (B0 + C0 - B2 - C2) * q11
               + (B1 - C2) * q12
               + (D0 + D1 - B0 - B1) * q20
               + (B1 + B2 - D1 - D2) * q22
               + (D1 - C0) * q30
               + (C2 + D2 - C0 - D0) * q31
               + (C2 - D1) * q32;
      J1 *= INV12S;
      float ct0 = CT[(size_t)i0 * n + j];
      float ct1 = CT[(size_t)(i0 + 1) * n + j];
      qf_out[idx0]     = -J0 - 1e-6f * z1a + 1e-8f * zc1 - 2e-11f * z4a + ct0
                         - 256.0f * (B2 - B0);
      qf_out[idx0 + n] = -J1 - 1e-6f * z1b + 1e-8f * zc2 - 2e-11f * z4b + ct1
                         - 256.0f * (C2 - C0);
    }
  } else {
    for (int t = lid; t < 40 * 40; t += NT) {   // s1
      int r = t / 40, c = t - r * 40;
      float v = 0.f;
      if ((ti - 4 + r) >= 1 && (ti - 4 + r) < n - 1 && (tj - 4 + c) >= 1 && (tj - 4 + c) < n - 1)
        v = C0F * (bufA[r * 43 + c + 1] + bufA[(r + 2) * 43 + c + 1] +
                   bufA[(r + 1) * 43 + c] + bufA[(r + 1) * 43 + c + 2] - bufB[r * 41 + c]);
      bufC[r * 41 + c] = v;
    }
    __syncthreads();
    for (int t = lid; t < 38 * 38; t += NT) {   // s2
      int r = t / 38, c = t - r * 38;
      float v = 0.f;
      if ((ti - 3 + r) >= 1 && (ti - 3 + r) < n - 1 && (tj - 3 + c) >= 1 && (tj - 3 + c) < n - 1)
        v = C0F * (bufC[r * 41 + c + 1] + bufC[(r + 2) * 41 + c + 1] +
                   bufC[(r + 1) * 41 + c] + bufC[(r + 1) * 41 + c + 2] - bufB[(r + 1) * 41 + c + 1]);
      bufD[r * 39 + c] = v;
    }
    __syncthreads();
    for (int t = lid; t < 36 * 36; t += NT) {   // Z
      int r = t / 36, c = t - r * 36;
      float v = 0.f;
      if ((ti - 2 + r) >= 1 && (ti - 2 + r) < n - 1 && (tj - 2 + c) >= 1 && (tj - 2 + c) < n - 1)
        v = (bufD[r * 39 + c + 1] + bufD[(r + 2) * 39 + c + 1] +
             bufD[(r + 1) * 39 + c] + bufD[(r + 1) * 39 + c + 2]) * INV_DX2
            - bufD[(r + 1) * 39 + c + 1] * CENTER;
      bufA[r * 37 + c] = v;
    }
    __syncthreads();
    for (int t = lid; t < 34 * 34; t += NT) {   // Z2
      int r = t / 34, c = t - r * 34;
      float v = 0.f;
      if ((ti - 1 + r) >= 1 && (ti - 1 + r) < n - 1 && (tj - 1 + c) >= 1 && (tj - 1 + c) < n - 1)
        v = (bufA[r * 37 + c + 1] + bufA[(r + 2) * 37 + c + 1] +
             bufA[(r + 1) * 37 + c] + bufA[(r + 1) * 37 + c + 2]) * INV_DX2
            - bufA[(r + 1) * 37 + c + 1] * CENTER;
      bufC[r * 35 + c] = v;
    }
    __syncthreads();
    int tx = lid & 31, ty = lid >> 5;
    #pragma unroll
    for (int s = 0; s < 2; s++) {
      int yy = ty + 16 * s;
      int i = ti + yy, j = tj + tx;
      if (i >= n || j >= n) continue;
      size_t idx = base + (size_t)i * n + j;
      int pr = yy + 3, pc = tx + 3;
      psi_out[idx] = bufD[pr * 39 + pc];
      float qv = 0.f;
      if (i >= 1 && i < n - 1 && j >= 1 && j < n - 1) {
        float z1v = bufA[(yy + 2) * 37 + tx + 2];
        int r2 = yy + 1, c2 = tx + 1;
        float z2v = bufC[r2 * 35 + c2];
        float z4 = (bufC[r2 * 35 + c2 - 1] + bufC[r2 * 35 + c2 + 1] +
                    bufC[(r2 - 1) * 35 + c2] + bufC[(r2 + 1) * 35 + c2]) * INV_DX2
                   - z2v * CENTER;
        float Amm = bufD[(pr - 1) * 39 + pc - 1], Am0 = bufD[(pr - 1) * 39 + pc],
              Amp = bufD[(pr - 1) * 39 + pc + 1];
        float A0m = bufD[pr * 39 + pc - 1], A0p = bufD[pr * 39 + pc + 1];
        float Apm = bufD[(pr + 1) * 39 + pc - 1], Ap0 = bufD[(pr + 1) * 39 + pc],
              App = bufD[(pr + 1) * 39 + pc + 1];
        int qr = yy + 4, qc = tx + 4;
        float J = (A0m - Am0) * bufB[(qr - 1) * 41 + qc - 1]
                + (Amm + A0m - Amp - A0p) * bufB[(qr - 1) * 41 + qc]
                + (Am0 - A0p) * bufB[(qr - 1) * 41 + qc + 1]
                + (Apm + Ap0 - Amm - Am0) * bufB[qr * 41 + qc - 1]
                + (Am0 + Amp - Ap0 - App) * bufB[qr * 41 + qc + 1]
                + (Ap0 - A0m) * bufB[(qr + 1) * 41 + qc - 1]
                + (A0p + App - A0m - Apm) * bufB[(qr + 1) * 41 + qc]
                + (A0p - Ap0) * bufB[(qr + 1) * 41 + qc + 1];
        J *= INV12S;
        float ct = CT[(size_t)i * n + j];
        qv = -J - 1e-6f * z1v + 1e-8f * z2v - 2e-11f * z4 + ct - 256.0f * (A0p - A0m);
      }
      qf_out[idx] = qv;
    }
  }
}

__global__ __launch_bounds__(NT) void mega_k(
    const float* __restrict__ psi, const float* __restrict__ Qg,
    const float* __restrict__ q1g, const float* __restrict__ CT,
    float* __restrict__ psi_out, float* __restrict__ qf_out) {
  __shared__ float bufA[42 * 43];
  __shared__ float bufB[40 * 41];
  __shared__ float bufC[40 * 41];
  __shared__ float bufD[38 * 39];
  int bx = blockIdx.x, by = blockIdx.y;
  int ti = by * 32, tj = bx * 32;
  int c0i = 16 * by - 3, c0j = 16 * bx - 3;
  size_t base = (size_t)blockIdx.z * (N0 * N0);
  const float* q1 = q1g + (size_t)blockIdx.z * (N1 * N1);
  int lid = threadIdx.y * 32 + threadIdx.x;
  bool inter = (bx >= 1 && bx <= 14 && by >= 1 && by <= 14);
  if (inter)
    mega_body<true>(psi + base, Qg + base, q1, CT, psi_out, qf_out,
                    ti, tj, c0i, c0j, base, lid, bufA, bufB, bufC, bufD);
  else
    mega_body<false>(psi + base, Qg + base, q1, CT, psi_out, qf_out,
                     ti, tj, c0i, c0j, base, lid, bufA, bufB, bufC, bufD);
}

extern "C" void kernel_launch(void* const* d_in, const int* in_sizes, int n_in,
                              void* d_out, int out_size, void* d_ws, size_t ws_size,
                              hipStream_t stream) {
  const float* PSIG = (const float*)d_in[1];
  const float* Q    = (const float*)d_in[2];
  const float* CT   = (const float*)d_in[3];

  float* ws = (float*)d_ws;
  size_t f0 = (size_t)NB * N0 * N0;
  size_t f1 = (size_t)NB * N1 * N1;
  float* pA  = ws;
  float* pB  = pA + f0;
  float* q1a = pB + f0;
  float* q1b = q1a + f1;

  dim3 blk(32, 16, 1), grd(17, 17, NB);

  drelaxR_k<<<grd, blk, 0, stream>>>(PSIG, Q, pA, q1a);      // cycle-1 down
  vleg_k<<<grd, blk, 0, stream>>>(pA, Q, q1a, pB, q1b);      // c1 up + c2 down
  float* psi_out = (float*)d_out;
  float* qf_out  = psi_out + f0;
  mega_k<<<grd, blk, 0, stream>>>(pB, Q, q1b, CT, psi_out, qf_out);  // c2 up + flux
}